// Round 10
// baseline (1033.228 us; speedup 1.0000x reference)
//
#include <hip/hip_runtime.h>
#include <hip/hip_bf16.h>
#include <hip/hip_fp16.h>
#include <cstddef>

// ---------------------------------------------------------------------------
// GNN layer (RED-GNN style), MI355X — round 10.
// vs round 9 (360 us = node 197 latency-bound + ~163 us of sort machinery):
// The obj-sort existed only to avoid fp32 atomics, but rounds 1/2 proved
// atomics are ~free (296 us with vs 298 us without). Drop the entire sort:
//   memset(agg) | fused_pre(packed fp16 + Br,Cq) |
//   edge_kernel(original order: linear meta, linear NT outputs,
//               per-lane atomicAdd into agg) | matmul64(agg @ W_h)
// 7 launches -> 4; hist/scan/scatter/meta buffers deleted.
// ---------------------------------------------------------------------------

typedef float    f32x4 __attribute__((ext_vector_type(4)));
typedef _Float16 f16x4 __attribute__((ext_vector_type(4)));

static __device__ __forceinline__ void nt_store4(float* p, float4 v) {
    f32x4 t = {v.x, v.y, v.z, v.w};
    __builtin_nontemporal_store(t, (f32x4*)p);
}
#define NT_STORE(p, v) __builtin_nontemporal_store((v), (p))

// Y[row] = X[row] @ W. W staged in LDS. block=256 = 4 rows x 64 cols.
__global__ void matmul64_kernel(const float* __restrict__ X,
                                const float* __restrict__ W,
                                float* __restrict__ Y, int nrows) {
    __shared__ float Wl[64][64];
    int tid = threadIdx.x;
    for (int i = tid; i < 4096; i += 256) Wl[i >> 6][i & 63] = W[i];
    __syncthreads();
    int col = tid & 63;
    int r4  = tid >> 6;
    for (long row = (long)blockIdx.x * 4 + r4; row < nrows;
         row += (long)gridDim.x * 4) {
        float xv  = X[row * 64 + col];
        float acc = 0.0f;
#pragma unroll
        for (int k = 0; k < 64; ++k)
            acc = fmaf(__shfl(xv, k, 64), Wl[k][col], acc);
        NT_STORE(&Y[row * 64 + col], acc);
    }
}

// Fused prologue. Block ranges:
//   [0, mmB)        : packed[row] = { fp16(hidden row) | fp16(hidden@Ws row) }
//   [mmB, mmB+relB) : Br = rela@Wr ; Cq = rela[q_rel]@Wqr + b   (fp32)
__global__ void fused_pre_kernel(const float* __restrict__ hidden,
                                 const float* __restrict__ Ws,
                                 _Float16* __restrict__ packed, int nnode,
                                 const float* __restrict__ rela,
                                 const float* __restrict__ Wr,
                                 const float* __restrict__ Wqr,
                                 const float* __restrict__ Wqr_b,
                                 const int* __restrict__ q_rel,
                                 float* __restrict__ Br,
                                 float* __restrict__ Cq, int nrel, int nq,
                                 int mmB) {
    __shared__ float W1[64][64];
    __shared__ float W2[64][64];
    int bid = blockIdx.x;
    int tid = threadIdx.x;

    if (bid < mmB) {
        for (int i = tid; i < 4096; i += 256) W1[i >> 6][i & 63] = Ws[i];
        __syncthreads();
        int col = tid & 63, r4 = tid >> 6;
        for (long row = (long)bid * 4 + r4; row < nnode; row += (long)mmB * 4) {
            float xv  = hidden[row * 64 + col];
            float acc = 0.0f;
#pragma unroll
            for (int k = 0; k < 64; ++k)
                acc = fmaf(__shfl(xv, k, 64), W1[k][col], acc);
            packed[row * 128 + col]      = (_Float16)xv;    // hidden row
            packed[row * 128 + 64 + col] = (_Float16)acc;   // hsWs row
        }
    } else {
        for (int i = tid; i < 4096; i += 256) {
            W1[i >> 6][i & 63] = Wr[i];
            W2[i >> 6][i & 63] = Wqr[i];
        }
        __syncthreads();
        int col = tid & 63, r4 = tid >> 6;
        int row = (bid - mmB) * 4 + r4;
        int total = nrel + nq;
        if (row < total) {
            if (row < nrel) {
                float xv  = rela[(size_t)row * 64 + col];
                float acc = 0.0f;
#pragma unroll
                for (int k = 0; k < 64; ++k)
                    acc = fmaf(__shfl(xv, k, 64), W1[k][col], acc);
                Br[(size_t)row * 64 + col] = acc;
            } else {
                int q  = row - nrel;
                int rr = q_rel[q];
                float xv  = rela[(size_t)rr * 64 + col];
                float acc = Wqr_b[col];
#pragma unroll
                for (int k = 0; k < 64; ++k)
                    acc = fmaf(__shfl(xv, k, 64), W2[k][col], acc);
                Cq[(size_t)q * 64 + col] = acc;
            }
        }
    }
}

// Edge pass, ORIGINAL order: 4 edges/wave, 16 lanes x 4 features per edge.
// Linear meta read, linear NT output writes, per-lane atomicAdd into agg.
__global__ void edge_kernel(const int* __restrict__ edges,
                            const _Float16* __restrict__ packed,
                            const float* __restrict__ rela,
                            const float* __restrict__ Br,
                            const float* __restrict__ Cq,
                            const float* __restrict__ w_alpha_w,
                            const float* __restrict__ w_alpha_b,
                            float* __restrict__ agg,
                            float* __restrict__ out_alpha,
                            float* __restrict__ out_message,
                            float* __restrict__ out_obj,
                            float* __restrict__ out_alpha_temp,
                            int nedge) {
    int tid  = threadIdx.x;
    int lane = tid & 63;
    int g    = lane >> 4;        // edge slot in wave (0..3)
    int s    = lane & 15;        // feature chunk (4 floats)
    long e0  = ((long)blockIdx.x * 4 + (tid >> 6)) * 4;
    if (e0 >= nedge) return;
    long e   = e0 + g;
    bool valid = (e < nedge);

    // 4 edges' metadata = 24 consecutive ints; coalesced load + broadcast.
    int md = 0;
    long mbase = e0 * 6;
    if (lane < 24 && (mbase + lane) < (long)nedge * 6) md = edges[mbase + lane];
    int r_idx = __shfl(md, g * 6 + 0, 64);
    int rel   = __shfl(md, g * 6 + 2, 64);
    int sub   = __shfl(md, g * 6 + 4, 64);
    int obj   = __shfl(md, g * 6 + 5, 64);
    if (!valid) { r_idx = 0; rel = 0; sub = 0; obj = 0; }

    // one 256 B packed region per edge: hidden half + hsWs half (fp16)
    const f16x4 hh = *(const f16x4*)(packed + (size_t)sub * 128 + s * 4);
    const f16x4 hw = *(const f16x4*)(packed + (size_t)sub * 128 + 64 + s * 4);
    const float4 b4 = *(const float4*)(Br   + (size_t)rel  * 64 + s * 4);
    const float4 c4 = *(const float4*)(Cq   + (size_t)r_idx* 64 + s * 4);
    const float4 rv = *(const float4*)(rela   + (size_t)rel * 64 + s * 4);
    const float4 wa = *(const float4*)(w_alpha_w + s * 4);

    float4 a4;
    a4.x = fmaxf((float)hw[0] + b4.x + c4.x, 0.0f);
    a4.y = fmaxf((float)hw[1] + b4.y + c4.y, 0.0f);
    a4.z = fmaxf((float)hw[2] + b4.z + c4.z, 0.0f);
    a4.w = fmaxf((float)hw[3] + b4.w + c4.w, 0.0f);

    float part = a4.x * wa.x + a4.y * wa.y + a4.z * wa.z + a4.w * wa.w;
    part += __shfl_xor(part, 1, 64);
    part += __shfl_xor(part, 2, 64);
    part += __shfl_xor(part, 4, 64);
    part += __shfl_xor(part, 8, 64);

    float at    = part + w_alpha_b[0];
    float alpha = 1.0f / (1.0f + __expf(-at));

    float4 m4;
    m4.x = alpha * ((float)hh[0] + rv.x);
    m4.y = alpha * ((float)hh[1] + rv.y);
    m4.z = alpha * ((float)hh[2] + rv.z);
    m4.w = alpha * ((float)hh[3] + rv.w);

    if (valid) {
        nt_store4(out_message + e * 64 + s * 4, m4);   // linear 1KB/wave
        float* ap = agg + (size_t)obj * 64 + s * 4;
        atomicAdd(ap + 0, m4.x);
        atomicAdd(ap + 1, m4.y);
        atomicAdd(ap + 2, m4.z);
        atomicAdd(ap + 3, m4.w);
        if (s == 0) {
            NT_STORE(&out_alpha[e], alpha);
            NT_STORE(&out_obj[e], (float)obj);
            NT_STORE(&out_alpha_temp[e], at);
        }
    }
}

extern "C" void kernel_launch(void* const* d_in, const int* in_sizes, int n_in,
                              void* d_out, int out_size, void* d_ws, size_t ws_size,
                              hipStream_t stream) {
    const int*   q_rel     = (const int*)d_in[1];
    const float* hidden    = (const float*)d_in[2];
    const int*   edges     = (const int*)d_in[3];
    const float* rela      = (const float*)d_in[5];
    const float* Ws        = (const float*)d_in[6];
    const float* Wr        = (const float*)d_in[7];
    const float* Wqr       = (const float*)d_in[8];
    const float* Wqr_b     = (const float*)d_in[9];
    const float* w_alpha_w = (const float*)d_in[10];
    const float* w_alpha_b = (const float*)d_in[11];
    const float* W_h       = (const float*)d_in[12];

    const int n_node = in_sizes[2] / 64;    // 100000
    const int n_edge = in_sizes[3] / 6;     // 1000000
    const int n_rel  = in_sizes[5] / 64;    // 401
    const int n_q    = in_sizes[1];         // 256

    // Output layout (all fp32, return order).
    float* out            = (float*)d_out;
    float* out_hidden_new = out;
    float* out_alpha      = out + (size_t)n_node * 64;
    float* out_message    = out_alpha + n_edge;
    float* out_obj        = out_message + (size_t)n_edge * 64;
    float* out_alpha_temp = out_obj + n_edge;

    // Workspace layout (~51.4 MB).
    _Float16* packed = (_Float16*)d_ws;                        // n_node*128 f16
    float*    agg    = (float*)(packed + (size_t)n_node * 128);// n_node*64 f32
    float*    Br     = agg + (size_t)n_node * 64;              // n_rel*64
    float*    Cq     = Br + (size_t)n_rel * 64;                // n_q*64

    // Zero the segment-sum accumulator (atomicAdd target, every call).
    (void)hipMemsetAsync(agg, 0, (size_t)n_node * 64 * sizeof(float), stream);

    // 1) fused prologue: packed fp16 table | Br,Cq
    const int mmB  = 2048;
    const int relB = (n_rel + n_q + 3) / 4;
    fused_pre_kernel<<<mmB + relB, 256, 0, stream>>>(
        hidden, Ws, packed, n_node,
        rela, Wr, Wqr, Wqr_b, q_rel, Br, Cq, n_rel, n_q, mmB);

    // 2) edge pass (original order) + atomic aggregation
    {
        int grid = (n_edge + 15) / 16;
        edge_kernel<<<grid, 256, 0, stream>>>(edges, packed, rela, Br, Cq,
                                              w_alpha_w, w_alpha_b, agg,
                                              out_alpha, out_message, out_obj,
                                              out_alpha_temp, n_edge);
    }

    // 3) hidden_new = agg @ W_h
    matmul64_kernel<<<2048, 256, 0, stream>>>(agg, W_h, out_hidden_new, n_node);
}

// Round 11
// 378.302 us; speedup vs baseline: 2.7312x; 2.7312x over previous
//
#include <hip/hip_runtime.h>
#include <hip/hip_bf16.h>
#include <hip/hip_fp16.h>
#include <cstddef>

// ---------------------------------------------------------------------------
// GNN layer (RED-GNN style), MI355X — round 11.
// vs round 10 (1033 us):
//  * Atomic fix: round 10's per-lane strided atomics made each atomic
//    instruction span 16 cache lines (16 line-RMWs/edge vs round 1's 4).
//    Now the wave shuffle-transposes message values and issues 4 atomic
//    instructions, each covering ONE edge's 64 contiguous dwords.
//  * hipMemsetAsync replaced by own grid-stride zero kernel (fillBuffer was
//    measured ~170 us regardless of size across rounds 2-10).
// Pipeline: zero(agg) | fused_pre(packed fp16 + Br,Cq) |
//           edge_kernel(original order, coalesced atomics) | matmul64(@W_h)
// ---------------------------------------------------------------------------

typedef float    f32x4 __attribute__((ext_vector_type(4)));
typedef _Float16 f16x4 __attribute__((ext_vector_type(4)));

static __device__ __forceinline__ void nt_store4(float* p, float4 v) {
    f32x4 t = {v.x, v.y, v.z, v.w};
    __builtin_nontemporal_store(t, (f32x4*)p);
}
#define NT_STORE(p, v) __builtin_nontemporal_store((v), (p))

// Fast zero fill (float4 NT stores, grid-stride).
__global__ void zero_kernel(float* __restrict__ p, size_t n4) {
    size_t i = (size_t)blockIdx.x * blockDim.x + threadIdx.x;
    size_t stride = (size_t)gridDim.x * blockDim.x;
    f32x4 z = {0.f, 0.f, 0.f, 0.f};
    for (; i < n4; i += stride)
        __builtin_nontemporal_store(z, (f32x4*)p + i);
}

// Y[row] = X[row] @ W. W staged in LDS. block=256 = 4 rows x 64 cols.
__global__ void matmul64_kernel(const float* __restrict__ X,
                                const float* __restrict__ W,
                                float* __restrict__ Y, int nrows) {
    __shared__ float Wl[64][64];
    int tid = threadIdx.x;
    for (int i = tid; i < 4096; i += 256) Wl[i >> 6][i & 63] = W[i];
    __syncthreads();
    int col = tid & 63;
    int r4  = tid >> 6;
    for (long row = (long)blockIdx.x * 4 + r4; row < nrows;
         row += (long)gridDim.x * 4) {
        float xv  = X[row * 64 + col];
        float acc = 0.0f;
#pragma unroll
        for (int k = 0; k < 64; ++k)
            acc = fmaf(__shfl(xv, k, 64), Wl[k][col], acc);
        NT_STORE(&Y[row * 64 + col], acc);
    }
}

// Fused prologue. Block ranges:
//   [0, mmB)        : packed[row] = { fp16(hidden row) | fp16(hidden@Ws row) }
//   [mmB, mmB+relB) : Br = rela@Wr ; Cq = rela[q_rel]@Wqr + b   (fp32)
__global__ void fused_pre_kernel(const float* __restrict__ hidden,
                                 const float* __restrict__ Ws,
                                 _Float16* __restrict__ packed, int nnode,
                                 const float* __restrict__ rela,
                                 const float* __restrict__ Wr,
                                 const float* __restrict__ Wqr,
                                 const float* __restrict__ Wqr_b,
                                 const int* __restrict__ q_rel,
                                 float* __restrict__ Br,
                                 float* __restrict__ Cq, int nrel, int nq,
                                 int mmB) {
    __shared__ float W1[64][64];
    __shared__ float W2[64][64];
    int bid = blockIdx.x;
    int tid = threadIdx.x;

    if (bid < mmB) {
        for (int i = tid; i < 4096; i += 256) W1[i >> 6][i & 63] = Ws[i];
        __syncthreads();
        int col = tid & 63, r4 = tid >> 6;
        for (long row = (long)bid * 4 + r4; row < nnode; row += (long)mmB * 4) {
            float xv  = hidden[row * 64 + col];
            float acc = 0.0f;
#pragma unroll
            for (int k = 0; k < 64; ++k)
                acc = fmaf(__shfl(xv, k, 64), W1[k][col], acc);
            packed[row * 128 + col]      = (_Float16)xv;    // hidden row
            packed[row * 128 + 64 + col] = (_Float16)acc;   // hsWs row
        }
    } else {
        for (int i = tid; i < 4096; i += 256) {
            W1[i >> 6][i & 63] = Wr[i];
            W2[i >> 6][i & 63] = Wqr[i];
        }
        __syncthreads();
        int col = tid & 63, r4 = tid >> 6;
        int row = (bid - mmB) * 4 + r4;
        int total = nrel + nq;
        if (row < total) {
            if (row < nrel) {
                float xv  = rela[(size_t)row * 64 + col];
                float acc = 0.0f;
#pragma unroll
                for (int k = 0; k < 64; ++k)
                    acc = fmaf(__shfl(xv, k, 64), W1[k][col], acc);
                Br[(size_t)row * 64 + col] = acc;
            } else {
                int q  = row - nrel;
                int rr = q_rel[q];
                float xv  = rela[(size_t)rr * 64 + col];
                float acc = Wqr_b[col];
#pragma unroll
                for (int k = 0; k < 64; ++k)
                    acc = fmaf(__shfl(xv, k, 64), W2[k][col], acc);
                Cq[(size_t)q * 64 + col] = acc;
            }
        }
    }
}

// Edge pass, ORIGINAL order: 4 edges/wave, 16 lanes x 4 features per edge.
// Atomic epilogue shuffle-transposed: 4 atomic instructions per wave, each
// covering ONE edge's 64 contiguous dwords (4 line-RMWs/edge).
__global__ void edge_kernel(const int* __restrict__ edges,
                            const _Float16* __restrict__ packed,
                            const float* __restrict__ rela,
                            const float* __restrict__ Br,
                            const float* __restrict__ Cq,
                            const float* __restrict__ w_alpha_w,
                            const float* __restrict__ w_alpha_b,
                            float* __restrict__ agg,
                            float* __restrict__ out_alpha,
                            float* __restrict__ out_message,
                            float* __restrict__ out_obj,
                            float* __restrict__ out_alpha_temp,
                            int nedge) {
    int tid  = threadIdx.x;
    int lane = tid & 63;
    int g    = lane >> 4;        // edge slot in wave (0..3)
    int s    = lane & 15;        // feature chunk (4 floats)
    long e0  = ((long)blockIdx.x * 4 + (tid >> 6)) * 4;
    if (e0 >= nedge) return;
    long e   = e0 + g;
    bool valid = (e < nedge);

    // 4 edges' metadata = 24 consecutive ints; coalesced load + broadcast.
    int md = 0;
    long mbase = e0 * 6;
    if (lane < 24 && (mbase + lane) < (long)nedge * 6) md = edges[mbase + lane];
    int r_idx = __shfl(md, g * 6 + 0, 64);
    int rel   = __shfl(md, g * 6 + 2, 64);
    int sub   = __shfl(md, g * 6 + 4, 64);
    int obj   = __shfl(md, g * 6 + 5, 64);
    if (!valid) { r_idx = 0; rel = 0; sub = 0; obj = 0; }

    // one 256 B packed region per edge: hidden half + hsWs half (fp16)
    const f16x4 hh = *(const f16x4*)(packed + (size_t)sub * 128 + s * 4);
    const f16x4 hw = *(const f16x4*)(packed + (size_t)sub * 128 + 64 + s * 4);
    const float4 b4 = *(const float4*)(Br   + (size_t)rel  * 64 + s * 4);
    const float4 c4 = *(const float4*)(Cq   + (size_t)r_idx* 64 + s * 4);
    const float4 rv = *(const float4*)(rela   + (size_t)rel * 64 + s * 4);
    const float4 wa = *(const float4*)(w_alpha_w + s * 4);

    float4 a4;
    a4.x = fmaxf((float)hw[0] + b4.x + c4.x, 0.0f);
    a4.y = fmaxf((float)hw[1] + b4.y + c4.y, 0.0f);
    a4.z = fmaxf((float)hw[2] + b4.z + c4.z, 0.0f);
    a4.w = fmaxf((float)hw[3] + b4.w + c4.w, 0.0f);

    float part = a4.x * wa.x + a4.y * wa.y + a4.z * wa.z + a4.w * wa.w;
    part += __shfl_xor(part, 1, 64);
    part += __shfl_xor(part, 2, 64);
    part += __shfl_xor(part, 4, 64);
    part += __shfl_xor(part, 8, 64);

    float at    = part + w_alpha_b[0];
    float alpha = 1.0f / (1.0f + __expf(-at));

    float4 m4;
    m4.x = alpha * ((float)hh[0] + rv.x);
    m4.y = alpha * ((float)hh[1] + rv.y);
    m4.z = alpha * ((float)hh[2] + rv.z);
    m4.w = alpha * ((float)hh[3] + rv.w);

    if (valid) {
        nt_store4(out_message + e * 64 + s * 4, m4);   // linear 1KB/wave
        if (s == 0) {
            NT_STORE(&out_alpha[e], alpha);
            NT_STORE(&out_obj[e], (float)obj);
            NT_STORE(&out_alpha_temp[e], at);
        }
    }

    // Coalesced atomic aggregation: edge k's 64 features by the whole wave.
    int comp = lane & 3;
#pragma unroll
    for (int k = 0; k < 4; ++k) {
        if (e0 + k < nedge) {
            int srcl = k * 16 + (lane >> 2);   // lane holding feature 'lane'
            float xk = __shfl(m4.x, srcl, 64);
            float yk = __shfl(m4.y, srcl, 64);
            float zk = __shfl(m4.z, srcl, 64);
            float wk = __shfl(m4.w, srcl, 64);
            float v  = (comp == 0) ? xk : (comp == 1) ? yk
                     : (comp == 2) ? zk : wk;
            int ok = __shfl(obj, k * 16, 64);
            atomicAdd(agg + (size_t)ok * 64 + lane, v);  // 64 contiguous dwords
        }
    }
}

extern "C" void kernel_launch(void* const* d_in, const int* in_sizes, int n_in,
                              void* d_out, int out_size, void* d_ws, size_t ws_size,
                              hipStream_t stream) {
    const int*   q_rel     = (const int*)d_in[1];
    const float* hidden    = (const float*)d_in[2];
    const int*   edges     = (const int*)d_in[3];
    const float* rela      = (const float*)d_in[5];
    const float* Ws        = (const float*)d_in[6];
    const float* Wr        = (const float*)d_in[7];
    const float* Wqr       = (const float*)d_in[8];
    const float* Wqr_b     = (const float*)d_in[9];
    const float* w_alpha_w = (const float*)d_in[10];
    const float* w_alpha_b = (const float*)d_in[11];
    const float* W_h       = (const float*)d_in[12];

    const int n_node = in_sizes[2] / 64;    // 100000
    const int n_edge = in_sizes[3] / 6;     // 1000000
    const int n_rel  = in_sizes[5] / 64;    // 401
    const int n_q    = in_sizes[1];         // 256

    // Output layout (all fp32, return order).
    float* out            = (float*)d_out;
    float* out_hidden_new = out;
    float* out_alpha      = out + (size_t)n_node * 64;
    float* out_message    = out_alpha + n_edge;
    float* out_obj        = out_message + (size_t)n_edge * 64;
    float* out_alpha_temp = out_obj + n_edge;

    // Workspace layout (~51.4 MB).
    _Float16* packed = (_Float16*)d_ws;                        // n_node*128 f16
    float*    agg    = (float*)(packed + (size_t)n_node * 128);// n_node*64 f32
    float*    Br     = agg + (size_t)n_node * 64;              // n_rel*64
    float*    Cq     = Br + (size_t)n_rel * 64;                // n_q*64

    // 0) zero the segment-sum accumulator (own kernel; fillBuffer is ~170us)
    zero_kernel<<<2048, 256, 0, stream>>>(agg, (size_t)n_node * 16);

    // 1) fused prologue: packed fp16 table | Br,Cq
    const int mmB  = 2048;
    const int relB = (n_rel + n_q + 3) / 4;
    fused_pre_kernel<<<mmB + relB, 256, 0, stream>>>(
        hidden, Ws, packed, n_node,
        rela, Wr, Wqr, Wqr_b, q_rel, Br, Cq, n_rel, n_q, mmB);

    // 2) edge pass (original order) + coalesced atomic aggregation
    {
        int grid = (n_edge + 15) / 16;
        edge_kernel<<<grid, 256, 0, stream>>>(edges, packed, rela, Br, Cq,
                                              w_alpha_w, w_alpha_b, agg,
                                              out_alpha, out_message, out_obj,
                                              out_alpha_temp, n_edge);
    }

    // 3) hidden_new = agg @ W_h
    matmul64_kernel<<<2048, 256, 0, stream>>>(agg, W_h, out_hidden_new, n_node);
}

// Round 12
// 274.896 us; speedup vs baseline: 3.7586x; 1.3762x over previous
//
#include <hip/hip_runtime.h>
#include <hip/hip_bf16.h>
#include <hip/hip_fp16.h>
#include <cstddef>

// ---------------------------------------------------------------------------
// GNN layer (RED-GNN style), MI355X — round 12.
// vs round 11 (378 us; edge 222 us pinned by 64M fp32 atomic dwords):
//  * agg is now fp16: packed __half2 atomics (global_atomic_pk_add_f16)
//    halve the atomic dword count (64M -> 32M) and the RMW line count
//    (4 -> 2 lines/edge). agg row = 128 B.
//  * zero(agg) folded into fused_pre as a 3rd block range; final matmul
//    reads fp16 agg. 4 launches -> 3.
// Pipeline: fused_pre(packed fp16 | Br,Cq | zero agg) |
//           edge_kernel(coalesced pk-fp16 atomics) | matmul64_f16(@W_h)
// ---------------------------------------------------------------------------

typedef float    f32x4 __attribute__((ext_vector_type(4)));
typedef _Float16 f16x4 __attribute__((ext_vector_type(4)));

static __device__ __forceinline__ void nt_store4(float* p, float4 v) {
    f32x4 t = {v.x, v.y, v.z, v.w};
    __builtin_nontemporal_store(t, (f32x4*)p);
}
#define NT_STORE(p, v) __builtin_nontemporal_store((v), (p))

// Fused prologue. Block ranges:
//   [0, mmB)             : packed[row] = { fp16(hidden) | fp16(hidden@Ws) }
//   [mmB, mmB+relB)      : Br = rela@Wr ; Cq = rela[q_rel]@Wqr + b (fp32)
//   [mmB+relB, +zB)      : zero agg (fp16, n_node*64 halfs)
__global__ void fused_pre_kernel(const float* __restrict__ hidden,
                                 const float* __restrict__ Ws,
                                 _Float16* __restrict__ packed, int nnode,
                                 const float* __restrict__ rela,
                                 const float* __restrict__ Wr,
                                 const float* __restrict__ Wqr,
                                 const float* __restrict__ Wqr_b,
                                 const int* __restrict__ q_rel,
                                 float* __restrict__ Br,
                                 float* __restrict__ Cq, int nrel, int nq,
                                 _Float16* __restrict__ agg,
                                 int mmB, int relB, int zB) {
    __shared__ float W1[64][64];
    __shared__ float W2[64][64];
    int bid = blockIdx.x;
    int tid = threadIdx.x;

    if (bid < mmB) {
        for (int i = tid; i < 4096; i += 256) W1[i >> 6][i & 63] = Ws[i];
        __syncthreads();
        int col = tid & 63, r4 = tid >> 6;
        for (long row = (long)bid * 4 + r4; row < nnode; row += (long)mmB * 4) {
            float xv  = hidden[row * 64 + col];
            float acc = 0.0f;
#pragma unroll
            for (int k = 0; k < 64; ++k)
                acc = fmaf(__shfl(xv, k, 64), W1[k][col], acc);
            packed[row * 128 + col]      = (_Float16)xv;    // hidden row
            packed[row * 128 + 64 + col] = (_Float16)acc;   // hsWs row
        }
    } else if (bid < mmB + relB) {
        for (int i = tid; i < 4096; i += 256) {
            W1[i >> 6][i & 63] = Wr[i];
            W2[i >> 6][i & 63] = Wqr[i];
        }
        __syncthreads();
        int col = tid & 63, r4 = tid >> 6;
        int row = (bid - mmB) * 4 + r4;
        int total = nrel + nq;
        if (row < total) {
            if (row < nrel) {
                float xv  = rela[(size_t)row * 64 + col];
                float acc = 0.0f;
#pragma unroll
                for (int k = 0; k < 64; ++k)
                    acc = fmaf(__shfl(xv, k, 64), W1[k][col], acc);
                Br[(size_t)row * 64 + col] = acc;
            } else {
                int q  = row - nrel;
                int rr = q_rel[q];
                float xv  = rela[(size_t)rr * 64 + col];
                float acc = Wqr_b[col];
#pragma unroll
                for (int k = 0; k < 64; ++k)
                    acc = fmaf(__shfl(xv, k, 64), W2[k][col], acc);
                Cq[(size_t)q * 64 + col] = acc;
            }
        }
    } else {
        // zero agg: n_node*64 halfs = n_node*8 x 16B
        size_t n16 = (size_t)nnode * 8;
        size_t i = (size_t)(bid - mmB - relB) * 256 + tid;
        size_t stride = (size_t)zB * 256;
        f32x4 z = {0.f, 0.f, 0.f, 0.f};
        for (; i < n16; i += stride)
            __builtin_nontemporal_store(z, (f32x4*)agg + i);
    }
}

// Edge pass, ORIGINAL order: 4 edges/wave, 16 lanes x 4 features per edge.
// Atomic epilogue: packed fp16 atomics, 2 edges per instruction
// (lanes 0-31 edge k, lanes 32-63 edge k+1; 32 half2 per edge, 128 B).
__global__ void edge_kernel(const int* __restrict__ edges,
                            const _Float16* __restrict__ packed,
                            const float* __restrict__ rela,
                            const float* __restrict__ Br,
                            const float* __restrict__ Cq,
                            const float* __restrict__ w_alpha_w,
                            const float* __restrict__ w_alpha_b,
                            _Float16* __restrict__ agg,
                            float* __restrict__ out_alpha,
                            float* __restrict__ out_message,
                            float* __restrict__ out_obj,
                            float* __restrict__ out_alpha_temp,
                            int nedge) {
    int tid  = threadIdx.x;
    int lane = tid & 63;
    int g    = lane >> 4;        // edge slot in wave (0..3)
    int s    = lane & 15;        // feature chunk (4 floats)
    long e0  = ((long)blockIdx.x * 4 + (tid >> 6)) * 4;
    if (e0 >= nedge) return;
    long e   = e0 + g;
    bool valid = (e < nedge);

    // 4 edges' metadata = 24 consecutive ints; coalesced load + broadcast.
    int md = 0;
    long mbase = e0 * 6;
    if (lane < 24 && (mbase + lane) < (long)nedge * 6) md = edges[mbase + lane];
    int r_idx = __shfl(md, g * 6 + 0, 64);
    int rel   = __shfl(md, g * 6 + 2, 64);
    int sub   = __shfl(md, g * 6 + 4, 64);
    int obj   = __shfl(md, g * 6 + 5, 64);
    if (!valid) { r_idx = 0; rel = 0; sub = 0; obj = 0; }

    // one 256 B packed region per edge: hidden half + hsWs half (fp16)
    const f16x4 hh = *(const f16x4*)(packed + (size_t)sub * 128 + s * 4);
    const f16x4 hw = *(const f16x4*)(packed + (size_t)sub * 128 + 64 + s * 4);
    const float4 b4 = *(const float4*)(Br   + (size_t)rel  * 64 + s * 4);
    const float4 c4 = *(const float4*)(Cq   + (size_t)r_idx* 64 + s * 4);
    const float4 rv = *(const float4*)(rela   + (size_t)rel * 64 + s * 4);
    const float4 wa = *(const float4*)(w_alpha_w + s * 4);

    float4 a4;
    a4.x = fmaxf((float)hw[0] + b4.x + c4.x, 0.0f);
    a4.y = fmaxf((float)hw[1] + b4.y + c4.y, 0.0f);
    a4.z = fmaxf((float)hw[2] + b4.z + c4.z, 0.0f);
    a4.w = fmaxf((float)hw[3] + b4.w + c4.w, 0.0f);

    float part = a4.x * wa.x + a4.y * wa.y + a4.z * wa.z + a4.w * wa.w;
    part += __shfl_xor(part, 1, 64);
    part += __shfl_xor(part, 2, 64);
    part += __shfl_xor(part, 4, 64);
    part += __shfl_xor(part, 8, 64);

    float at    = part + w_alpha_b[0];
    float alpha = 1.0f / (1.0f + __expf(-at));

    float4 m4;
    m4.x = alpha * ((float)hh[0] + rv.x);
    m4.y = alpha * ((float)hh[1] + rv.y);
    m4.z = alpha * ((float)hh[2] + rv.z);
    m4.w = alpha * ((float)hh[3] + rv.w);

    if (valid) {
        nt_store4(out_message + e * 64 + s * 4, m4);   // linear 1KB/wave
        if (s == 0) {
            NT_STORE(&out_alpha[e], alpha);
            NT_STORE(&out_obj[e], (float)obj);
            NT_STORE(&out_alpha_temp[e], at);
        }
    }

    // Packed fp16 atomic aggregation: 2 edges per instruction.
    // half2 index h covers features (2h, 2h+1): source lane k*16 + (h>>1),
    // comps (x,y) for even h, (z,w) for odd h.
    int h = lane & 31;
#pragma unroll
    for (int i = 0; i < 2; ++i) {
        int k = i * 2 + (lane >> 5);       // edge slot 0..3
        if (e0 + k < nedge) {
            int srcl = k * 16 + (h >> 1);
            float xk = __shfl(m4.x, srcl, 64);
            float yk = __shfl(m4.y, srcl, 64);
            float zk = __shfl(m4.z, srcl, 64);
            float wk = __shfl(m4.w, srcl, 64);
            __half2 v = (h & 1) ? __floats2half2_rn(zk, wk)
                                : __floats2half2_rn(xk, yk);
            int ok = __shfl(obj, k * 16, 64);
            unsafeAtomicAdd((__half2*)(agg + (size_t)ok * 64) + h, v);
        }
    }
}

// hidden_new = agg(fp16) @ W_h. W staged in LDS. block=256 = 4 rows x 64 cols.
__global__ void matmul64_f16_kernel(const _Float16* __restrict__ X,
                                    const float* __restrict__ W,
                                    float* __restrict__ Y, int nrows) {
    __shared__ float Wl[64][64];
    int tid = threadIdx.x;
    for (int i = tid; i < 4096; i += 256) Wl[i >> 6][i & 63] = W[i];
    __syncthreads();
    int col = tid & 63;
    int r4  = tid >> 6;
    for (long row = (long)blockIdx.x * 4 + r4; row < nrows;
         row += (long)gridDim.x * 4) {
        float xv  = (float)X[row * 64 + col];
        float acc = 0.0f;
#pragma unroll
        for (int k = 0; k < 64; ++k)
            acc = fmaf(__shfl(xv, k, 64), Wl[k][col], acc);
        NT_STORE(&Y[row * 64 + col], acc);
    }
}

extern "C" void kernel_launch(void* const* d_in, const int* in_sizes, int n_in,
                              void* d_out, int out_size, void* d_ws, size_t ws_size,
                              hipStream_t stream) {
    const int*   q_rel     = (const int*)d_in[1];
    const float* hidden    = (const float*)d_in[2];
    const int*   edges     = (const int*)d_in[3];
    const float* rela      = (const float*)d_in[5];
    const float* Ws        = (const float*)d_in[6];
    const float* Wr        = (const float*)d_in[7];
    const float* Wqr       = (const float*)d_in[8];
    const float* Wqr_b     = (const float*)d_in[9];
    const float* w_alpha_w = (const float*)d_in[10];
    const float* w_alpha_b = (const float*)d_in[11];
    const float* W_h       = (const float*)d_in[12];

    const int n_node = in_sizes[2] / 64;    // 100000
    const int n_edge = in_sizes[3] / 6;     // 1000000
    const int n_rel  = in_sizes[5] / 64;    // 401
    const int n_q    = in_sizes[1];         // 256

    // Output layout (all fp32, return order).
    float* out            = (float*)d_out;
    float* out_hidden_new = out;
    float* out_alpha      = out + (size_t)n_node * 64;
    float* out_message    = out_alpha + n_edge;
    float* out_obj        = out_message + (size_t)n_edge * 64;
    float* out_alpha_temp = out_obj + n_edge;

    // Workspace layout (~38.7 MB).
    _Float16* packed = (_Float16*)d_ws;                         // n_node*128 f16
    _Float16* agg    = packed + (size_t)n_node * 128;           // n_node*64 f16
    float*    Br     = (float*)(agg + (size_t)n_node * 64);     // n_rel*64
    float*    Cq     = Br + (size_t)n_rel * 64;                 // n_q*64

    // 1) fused prologue: packed fp16 table | Br,Cq | zero agg
    const int mmB  = 2048;
    const int relB = (n_rel + n_q + 3) / 4;
    const int zB   = 512;
    fused_pre_kernel<<<mmB + relB + zB, 256, 0, stream>>>(
        hidden, Ws, packed, n_node,
        rela, Wr, Wqr, Wqr_b, q_rel, Br, Cq, n_rel, n_q,
        agg, mmB, relB, zB);

    // 2) edge pass (original order) + packed fp16 atomic aggregation
    {
        int grid = (n_edge + 15) / 16;
        edge_kernel<<<grid, 256, 0, stream>>>(edges, packed, rela, Br, Cq,
                                              w_alpha_w, w_alpha_b, agg,
                                              out_alpha, out_message, out_obj,
                                              out_alpha_temp, n_edge);
    }

    // 3) hidden_new = agg @ W_h
    matmul64_f16_kernel<<<2048, 256, 0, stream>>>(agg, W_h, out_hidden_new,
                                                  n_node);
}

// Round 13
// 266.819 us; speedup vs baseline: 3.8724x; 1.0303x over previous
//
#include <hip/hip_runtime.h>
#include <hip/hip_bf16.h>
#include <hip/hip_fp16.h>
#include <cstddef>

// ---------------------------------------------------------------------------
// GNN layer (RED-GNN style), MI355X — round 13.
// vs round 12 (275 us; edge 170 = ~118 base + ~52 atomics):
//  * edge_kernel: 8 edges/wave (8 lanes x 8 features, 16B loads everywhere).
//    One 48-int meta load; 8 packed-row gathers in flight (2x MLP on the one
//    random stream); 3-step reduce shared by 8 edges; Br/Cq/rela as fp16
//    tables (one 16B load each); atomic transpose via LDS (conflict-free)
//    instead of shuffles. Waves halved, per-edge instructions ~halved.
//  * Atomic scheme unchanged: 4 pk-fp16 atomic instrs/wave, 2 edges each,
//    128 B contiguous per edge.
// Pipeline: fused_pre(packed fp16 | Br16,Cq16,rela16 | zero agg) |
//           edge_kernel | matmul64_f16(@W_h)
// ---------------------------------------------------------------------------

typedef float    f32x4 __attribute__((ext_vector_type(4)));
typedef _Float16 f16x8 __attribute__((ext_vector_type(8)));

#define NT_STORE(p, v) __builtin_nontemporal_store((v), (p))

// Fused prologue. Block ranges:
//   [0, mmB)        : packed[row] = { fp16(hidden) | fp16(hidden@Ws) }
//   [mmB, mmB+relB) : Br16 = fp16(rela@Wr); rela16 = fp16(rela);
//                     Cq16 = fp16(rela[q_rel]@Wqr + b)
//   [mmB+relB, +zB) : zero agg (fp16, n_node*64 halfs)
__global__ void fused_pre_kernel(const float* __restrict__ hidden,
                                 const float* __restrict__ Ws,
                                 _Float16* __restrict__ packed, int nnode,
                                 const float* __restrict__ rela,
                                 const float* __restrict__ Wr,
                                 const float* __restrict__ Wqr,
                                 const float* __restrict__ Wqr_b,
                                 const int* __restrict__ q_rel,
                                 _Float16* __restrict__ Br16,
                                 _Float16* __restrict__ Cq16,
                                 _Float16* __restrict__ rela16,
                                 int nrel, int nq,
                                 _Float16* __restrict__ agg,
                                 int mmB, int relB, int zB) {
    __shared__ float W1[64][64];
    __shared__ float W2[64][64];
    int bid = blockIdx.x;
    int tid = threadIdx.x;

    if (bid < mmB) {
        for (int i = tid; i < 4096; i += 256) W1[i >> 6][i & 63] = Ws[i];
        __syncthreads();
        int col = tid & 63, r4 = tid >> 6;
        for (long row = (long)bid * 4 + r4; row < nnode; row += (long)mmB * 4) {
            float xv  = hidden[row * 64 + col];
            float acc = 0.0f;
#pragma unroll
            for (int k = 0; k < 64; ++k)
                acc = fmaf(__shfl(xv, k, 64), W1[k][col], acc);
            packed[row * 128 + col]      = (_Float16)xv;    // hidden row
            packed[row * 128 + 64 + col] = (_Float16)acc;   // hsWs row
        }
    } else if (bid < mmB + relB) {
        for (int i = tid; i < 4096; i += 256) {
            W1[i >> 6][i & 63] = Wr[i];
            W2[i >> 6][i & 63] = Wqr[i];
        }
        __syncthreads();
        int col = tid & 63, r4 = tid >> 6;
        int row = (bid - mmB) * 4 + r4;
        int total = nrel + nq;
        if (row < total) {
            if (row < nrel) {
                float xv  = rela[(size_t)row * 64 + col];
                float acc = 0.0f;
#pragma unroll
                for (int k = 0; k < 64; ++k)
                    acc = fmaf(__shfl(xv, k, 64), W1[k][col], acc);
                Br16[(size_t)row * 64 + col]   = (_Float16)acc;
                rela16[(size_t)row * 64 + col] = (_Float16)xv;
            } else {
                int q  = row - nrel;
                int rr = q_rel[q];
                float xv  = rela[(size_t)rr * 64 + col];
                float acc = Wqr_b[col];
#pragma unroll
                for (int k = 0; k < 64; ++k)
                    acc = fmaf(__shfl(xv, k, 64), W2[k][col], acc);
                Cq16[(size_t)q * 64 + col] = (_Float16)acc;
            }
        }
    } else {
        // zero agg: n_node*64 halfs = n_node*8 x 16B
        size_t n16 = (size_t)nnode * 8;
        size_t i = (size_t)(bid - mmB - relB) * 256 + tid;
        size_t stride = (size_t)zB * 256;
        f32x4 z = {0.f, 0.f, 0.f, 0.f};
        for (; i < n16; i += stride)
            __builtin_nontemporal_store(z, (f32x4*)agg + i);
    }
}

// Edge pass: 8 edges/wave, 8 lanes x 8 features per edge, all loads 16B.
__global__ void edge_kernel(const int* __restrict__ edges,
                            const _Float16* __restrict__ packed,
                            const _Float16* __restrict__ rela16,
                            const _Float16* __restrict__ Br16,
                            const _Float16* __restrict__ Cq16,
                            const float* __restrict__ w_alpha_w,
                            const float* __restrict__ w_alpha_b,
                            _Float16* __restrict__ agg,
                            float* __restrict__ out_alpha,
                            float* __restrict__ out_message,
                            float* __restrict__ out_obj,
                            float* __restrict__ out_alpha_temp,
                            int nedge) {
    __shared__ __align__(16) _Float16 sm[4][8][64];   // [wave][edge][feat] 4KB
    int tid  = threadIdx.x;
    int wv   = tid >> 6;
    int lane = tid & 63;
    int g    = lane >> 3;        // edge slot in wave (0..7)
    int s    = lane & 7;         // feature octet (8 halfs)
    long e0  = ((long)blockIdx.x * 4 + wv) * 8;
    if ((long)blockIdx.x * 32 >= nedge) return;   // block-uniform guard
    long e   = e0 + g;
    bool valid = (e < nedge);

    // 8 edges' metadata = 48 consecutive ints; coalesced load + broadcast.
    int md = 0;
    long mbase = e0 * 6;
    if (lane < 48 && (mbase + lane) < (long)nedge * 6) md = edges[mbase + lane];
    int r_idx = __shfl(md, g * 6 + 0, 64);
    int rel   = __shfl(md, g * 6 + 2, 64);
    int sub   = __shfl(md, g * 6 + 4, 64);
    int obj   = __shfl(md, g * 6 + 5, 64);
    if (!valid) { r_idx = 0; rel = 0; sub = 0; obj = 0; }

    // All gathers are one 16B dwordx4 per lane; 8 packed rows in flight/wave.
    const f16x8 hh = *(const f16x8*)(packed + (size_t)sub * 128 + s * 8);
    const f16x8 hw = *(const f16x8*)(packed + (size_t)sub * 128 + 64 + s * 8);
    const f16x8 br = *(const f16x8*)(Br16   + (size_t)rel   * 64 + s * 8);
    const f16x8 cq = *(const f16x8*)(Cq16   + (size_t)r_idx * 64 + s * 8);
    const f16x8 rv = *(const f16x8*)(rela16 + (size_t)rel   * 64 + s * 8);
    const f32x4 wa0 = *(const f32x4*)(w_alpha_w + s * 8);
    const f32x4 wa1 = *(const f32x4*)(w_alpha_w + s * 8 + 4);

    float dot = 0.0f;
#pragma unroll
    for (int j = 0; j < 8; ++j) {
        float a  = fmaxf((float)hw[j] + (float)br[j] + (float)cq[j], 0.0f);
        float wj = (j < 4) ? wa0[j] : wa1[j - 4];
        dot = fmaf(a, wj, dot);
    }
    // 3-step reduce within each 8-lane group (shared by 8 edges)
    dot += __shfl_xor(dot, 1, 64);
    dot += __shfl_xor(dot, 2, 64);
    dot += __shfl_xor(dot, 4, 64);

    float at    = dot + w_alpha_b[0];
    float alpha = 1.0f / (1.0f + __expf(-at));

    float m[8];
#pragma unroll
    for (int j = 0; j < 8; ++j)
        m[j] = alpha * ((float)hh[j] + (float)rv[j]);

    if (valid) {
        f32x4 m0 = {m[0], m[1], m[2], m[3]};
        f32x4 m1 = {m[4], m[5], m[6], m[7]};
        __builtin_nontemporal_store(m0, (f32x4*)(out_message + e * 64 + s * 8));
        __builtin_nontemporal_store(m1, (f32x4*)(out_message + e * 64 + s * 8 + 4));
        if (s == 0) {
            NT_STORE(&out_alpha[e], alpha);
            NT_STORE(&out_obj[e], (float)obj);
            NT_STORE(&out_alpha_temp[e], at);
        }
    }

    // Stage fp16 message rows in LDS, then coalesced pk-fp16 atomics:
    // 4 instructions/wave, each covering 2 edges x 128 B contiguous.
    f16x8 mh;
#pragma unroll
    for (int j = 0; j < 8; ++j) mh[j] = (_Float16)m[j];
    *(f16x8*)&sm[wv][g][s * 8] = mh;
    __syncthreads();
#pragma unroll
    for (int i = 0; i < 4; ++i) {
        int k = 2 * i + (lane >> 5);       // edge slot 0..7
        int h = lane & 31;                 // half2 index within row
        if (e0 + k < nedge) {
            __half2 v = *(__half2*)&sm[wv][k][h * 2];
            int ok = __shfl(obj, k * 8, 64);
            unsafeAtomicAdd((__half2*)(agg + (size_t)ok * 64) + h, v);
        }
    }
}

// hidden_new = agg(fp16) @ W_h. W staged in LDS. block=256 = 4 rows x 64 cols.
__global__ void matmul64_f16_kernel(const _Float16* __restrict__ X,
                                    const float* __restrict__ W,
                                    float* __restrict__ Y, int nrows) {
    __shared__ float Wl[64][64];
    int tid = threadIdx.x;
    for (int i = tid; i < 4096; i += 256) Wl[i >> 6][i & 63] = W[i];
    __syncthreads();
    int col = tid & 63;
    int r4  = tid >> 6;
    for (long row = (long)blockIdx.x * 4 + r4; row < nrows;
         row += (long)gridDim.x * 4) {
        float xv  = (float)X[row * 64 + col];
        float acc = 0.0f;
#pragma unroll
        for (int k = 0; k < 64; ++k)
            acc = fmaf(__shfl(xv, k, 64), Wl[k][col], acc);
        NT_STORE(&Y[row * 64 + col], acc);
    }
}

extern "C" void kernel_launch(void* const* d_in, const int* in_sizes, int n_in,
                              void* d_out, int out_size, void* d_ws, size_t ws_size,
                              hipStream_t stream) {
    const int*   q_rel     = (const int*)d_in[1];
    const float* hidden    = (const float*)d_in[2];
    const int*   edges     = (const int*)d_in[3];
    const float* rela      = (const float*)d_in[5];
    const float* Ws        = (const float*)d_in[6];
    const float* Wr        = (const float*)d_in[7];
    const float* Wqr       = (const float*)d_in[8];
    const float* Wqr_b     = (const float*)d_in[9];
    const float* w_alpha_w = (const float*)d_in[10];
    const float* w_alpha_b = (const float*)d_in[11];
    const float* W_h       = (const float*)d_in[12];

    const int n_node = in_sizes[2] / 64;    // 100000
    const int n_edge = in_sizes[3] / 6;     // 1000000
    const int n_rel  = in_sizes[5] / 64;    // 401
    const int n_q    = in_sizes[1];         // 256

    // Output layout (all fp32, return order).
    float* out            = (float*)d_out;
    float* out_hidden_new = out;
    float* out_alpha      = out + (size_t)n_node * 64;
    float* out_message    = out_alpha + n_edge;
    float* out_obj        = out_message + (size_t)n_edge * 64;
    float* out_alpha_temp = out_obj + n_edge;

    // Workspace layout (~38.6 MB, all 16B-aligned offsets).
    _Float16* packed = (_Float16*)d_ws;                         // n_node*128
    _Float16* agg    = packed + (size_t)n_node * 128;           // n_node*64
    _Float16* Br16   = agg + (size_t)n_node * 64;               // n_rel*64
    _Float16* Cq16   = Br16 + (size_t)n_rel * 64;               // n_q*64
    _Float16* rela16 = Cq16 + (size_t)n_q * 64;                 // n_rel*64

    // 1) fused prologue: packed fp16 table | Br16,Cq16,rela16 | zero agg
    const int mmB  = 2048;
    const int relB = (n_rel + n_q + 3) / 4;
    const int zB   = 512;
    fused_pre_kernel<<<mmB + relB + zB, 256, 0, stream>>>(
        hidden, Ws, packed, n_node,
        rela, Wr, Wqr, Wqr_b, q_rel, Br16, Cq16, rela16, n_rel, n_q,
        agg, mmB, relB, zB);

    // 2) edge pass: 8 edges/wave, LDS-transposed pk-fp16 atomics
    {
        int grid = (n_edge + 31) / 32;
        edge_kernel<<<grid, 256, 0, stream>>>(edges, packed, rela16, Br16, Cq16,
                                              w_alpha_w, w_alpha_b, agg,
                                              out_alpha, out_message, out_obj,
                                              out_alpha_temp, n_edge);
    }

    // 3) hidden_new = agg @ W_h
    matmul64_f16_kernel<<<2048, 256, 0, stream>>>(agg, W_h, out_hidden_new,
                                                  n_node);
}